// Round 1
// baseline (4176.387 us; speedup 1.0000x reference)
//
#include <hip/hip_runtime.h>
#include <hip/hip_bf16.h>

typedef __bf16 bf16x8 __attribute__((ext_vector_type(8)));
typedef float  f32x4  __attribute__((ext_vector_type(4)));

#define Bq 64
#define Sq 512
#define Iq 512
#define Hq 1024
#define TSTEPS 511
#define MB 16          // batches per group
#define NCOLS 32       // h-columns per block
#define SHq (Sq*Hq)

__device__ inline unsigned short f2bf(float f){ return __builtin_bit_cast(unsigned short, (__bf16)f); }
__device__ inline float bf2f(unsigned short u){ return (float)__builtin_bit_cast(__bf16, u); }

// swizzled LDS byte addresses (break the 2048B/1024B row-stride bank conflict)
__device__ inline unsigned ah_addr(unsigned row, unsigned k){ return ((row<<11) + (k<<1)) ^ ((row&7)<<4); }
__device__ inline unsigned ax_addr(unsigned row, unsigned k){ return ((row<<10) + (k<<1)) ^ ((row&7)<<4); }

__device__ inline bf16x8 load_wfrag(const float* p){
  float4 a = *(const float4*)p;
  float4 b = *(const float4*)(p+4);
  bf16x8 w;
  w[0]=(__bf16)a.x; w[1]=(__bf16)a.y; w[2]=(__bf16)a.z; w[3]=(__bf16)a.w;
  w[4]=(__bf16)b.x; w[5]=(__bf16)b.y; w[6]=(__bf16)b.z; w[7]=(__bf16)b.w;
  return w;
}

__device__ inline void group_barrier(unsigned* bar, unsigned target){
  __syncthreads();   // all waves drain their global stores (compiler emits vmcnt(0) before s_barrier)
  if (threadIdx.x == 0) {
    __hip_atomic_fetch_add(bar, 1u, __ATOMIC_ACQ_REL, __HIP_MEMORY_SCOPE_AGENT);
    unsigned v;
    do {
      v = __hip_atomic_load(bar, __ATOMIC_ACQUIRE, __HIP_MEMORY_SCOPE_AGENT);
      if (v >= target) break;
      __builtin_amdgcn_s_sleep(1);
    } while (1);
  }
  __syncthreads();
}

__global__ __launch_bounds__(512, 2) void gru_kernel(
    const float* __restrict__ x, const float* __restrict__ h0,
    const float* __restrict__ w_ir, const float* __restrict__ w_iz, const float* __restrict__ w_in_,
    const float* __restrict__ b_ir, const float* __restrict__ b_iz, const float* __restrict__ b_in_,
    const float* __restrict__ w_hr, const float* __restrict__ w_hz, const float* __restrict__ w_hn,
    const float* __restrict__ b_hr, const float* __restrict__ b_hz, const float* __restrict__ b_hn,
    float* __restrict__ out, void* ws)
{
  __shared__ unsigned short Ah[MB*Hq];   // 32 KB, swizzled, bf16 h rows of this group
  __shared__ unsigned short Ax[MB*Iq];   // 16 KB, swizzled, bf16 x_t rows of this group
  __shared__ float P[2*4*4*256];         // 32 KB partials: [ct][tile][q][16x16]
  __shared__ float biasR[NCOLS], biasZ[NCOLS], biasNX[NCOLS], biasNH[NCOLS];

  const unsigned tid    = threadIdx.x;
  const unsigned bid    = blockIdx.x;
  const unsigned g      = bid & 3;        // batch group (interleaved -> 2 XCDs per group)
  const unsigned colblk = bid >> 2;       // 0..31
  const unsigned colbase= colblk * NCOLS;
  const unsigned lane   = tid & 63;
  const unsigned wave   = tid >> 6;
  const unsigned ct     = wave >> 2;      // which 16-col tile (0/1)
  const unsigned q      = wave & 3;       // K quarter
  const unsigned l15    = lane & 15;
  const unsigned l4     = lane >> 4;

  unsigned* bar = (unsigned*)((char*)ws + g*256);
  unsigned short* hb0 = (unsigned short*)((char*)ws + 1024);
  unsigned short* hb1 = hb0 + Bq*Hq;

  if (tid < NCOLS) {
    unsigned c = colbase + tid;
    biasR[tid]  = b_ir[c] + b_hr[c];
    biasZ[tid]  = b_iz[c] + b_hz[c];
    biasNX[tid] = b_in_[c];
    biasNH[tid] = b_hn[c];
  }

  // ---- init: h0 -> hbuf0 (bf16, agent-visible) and out[:,0,:] = h0 ----
  if (colblk == 0) {
    #pragma unroll
    for (int i = 0; i < 16; ++i) {
      unsigned flat = tid + i*512;            // 16 rows x 512 pairs
      unsigned row  = flat >> 9;
      unsigned col0 = (flat & 511) << 1;
      unsigned b    = g*MB + row;
      const float2 v = *(const float2*)(h0 + (size_t)b*Hq + col0);
      *(float2*)(out + (size_t)b*SHq + col0) = v;
      unsigned pv = (unsigned)f2bf(v.x) | ((unsigned)f2bf(v.y) << 16);
      __hip_atomic_store((unsigned*)(hb0 + (size_t)b*Hq + col0), pv,
                         __ATOMIC_RELAXED, __HIP_MEMORY_SCOPE_AGENT);
    }
  }

  // ---- stationary weight fragments in registers (144 VGPR/wave) ----
  // B-frag layout (16x16x32): col = lane&15, k = (lane>>4)*8 + [0..7]  -> 8 contiguous floats of W[hcol][k..]
  const unsigned hcf = colbase + ct*16 + l15;
  bf16x8 wR[12], wZ[12], wNH[8], wNX[4];
  #pragma unroll
  for (int j = 0; j < 12; ++j) {
    unsigned ks = q*12 + j;                   // r/z ksteps: 0..15 = x-part (K=512), 16..47 = h-part (K=1024)
    const float *pr, *pz;
    if (ks < 16) { pr = w_ir + (size_t)hcf*Iq + ks*32;      pz = w_iz + (size_t)hcf*Iq + ks*32; }
    else         { pr = w_hr + (size_t)hcf*Hq + (ks-16)*32; pz = w_hz + (size_t)hcf*Hq + (ks-16)*32; }
    wR[j] = load_wfrag(pr + l4*8);
    wZ[j] = load_wfrag(pz + l4*8);
  }
  #pragma unroll
  for (int j = 0; j < 8; ++j) { unsigned ks = q*8 + j; wNH[j] = load_wfrag(w_hn  + (size_t)hcf*Hq + ks*32 + l4*8); }
  #pragma unroll
  for (int j = 0; j < 4; ++j) { unsigned ks = q*4 + j; wNX[j] = load_wfrag(w_in_ + (size_t)hcf*Iq + ks*32 + l4*8); }

  group_barrier(bar, 32u);   // h0 visible to whole group

  unsigned cur = 0;
  for (int t = 0; t < TSTEPS; ++t) {
    const unsigned short* hs = cur ? hb1 : hb0;
    unsigned short*       hd = cur ? hb0 : hb1;

    // ---- stage h (agent atomics, 8B) and x_t (f32 -> bf16) into swizzled LDS ----
    {
      const unsigned row = tid >> 5, li = tid & 31;
      const unsigned long long* srcs = (const unsigned long long*)(hs + (size_t)(g*MB+row)*Hq) + li*8;
      #pragma unroll
      for (int i = 0; i < 8; ++i) {
        unsigned long long v = __hip_atomic_load(srcs + i, __ATOMIC_RELAXED, __HIP_MEMORY_SCOPE_AGENT);
        *(unsigned long long*)((char*)Ah + ah_addr(row, li*32 + i*4)) = v;
      }
      const float* xs = x + ((size_t)(g*MB+row)*Sq + (size_t)(t+1))*Iq + li*16;
      #pragma unroll
      for (int i = 0; i < 4; ++i) {
        float4 v = *(const float4*)(xs + i*4);
        unsigned long long pv = (unsigned long long)f2bf(v.x)
                              | ((unsigned long long)f2bf(v.y) << 16)
                              | ((unsigned long long)f2bf(v.z) << 32)
                              | ((unsigned long long)f2bf(v.w) << 48);
        *(unsigned long long*)((char*)Ax + ax_addr(row, li*16 + i*4)) = pv;
      }
    }
    __syncthreads();

    // ---- MFMA: 36 ksteps/wave into 4 accumulators ----
    f32x4 accR={0.f,0.f,0.f,0.f}, accZ={0.f,0.f,0.f,0.f}, accNX={0.f,0.f,0.f,0.f}, accNH={0.f,0.f,0.f,0.f};
    #pragma unroll
    for (int j = 0; j < 12; ++j) {
      unsigned ks = q*12 + j;
      bf16x8 a;
      if (ks < 16) a = *(const bf16x8*)((char*)Ax + ax_addr(l15, ks*32 + l4*8));
      else         a = *(const bf16x8*)((char*)Ah + ah_addr(l15, (ks-16)*32 + l4*8));
      accR = __builtin_amdgcn_mfma_f32_16x16x32_bf16(a, wR[j], accR, 0, 0, 0);
      accZ = __builtin_amdgcn_mfma_f32_16x16x32_bf16(a, wZ[j], accZ, 0, 0, 0);
    }
    #pragma unroll
    for (int j = 0; j < 8; ++j) {
      unsigned ks = q*8 + j;
      bf16x8 a = *(const bf16x8*)((char*)Ah + ah_addr(l15, ks*32 + l4*8));
      accNH = __builtin_amdgcn_mfma_f32_16x16x32_bf16(a, wNH[j], accNH, 0, 0, 0);
    }
    #pragma unroll
    for (int j = 0; j < 4; ++j) {
      unsigned ks = q*4 + j;
      bf16x8 a = *(const bf16x8*)((char*)Ax + ax_addr(l15, ks*32 + l4*8));
      accNX = __builtin_amdgcn_mfma_f32_16x16x32_bf16(a, wNX[j], accNX, 0, 0, 0);
    }

    // ---- partials to LDS (C layout: col=lane&15, row=(lane>>4)*4+i) ----
    {
      float* base = P + (ct*16 + q)*256;      // ((ct*4+tile)*4+q)*256 with tile stride 1024
      #pragma unroll
      for (int i = 0; i < 4; ++i) {
        unsigned e = (l4*4 + i)*16 + l15;
        base[0    + e] = accR[i];
        base[1024 + e] = accZ[i];
        base[2048 + e] = accNX[i];
        base[3072 + e] = accNH[i];
      }
    }
    __syncthreads();

    // ---- reduce + gates + stores (256 threads, 2 cols each) ----
    if (tid < 256) {
      const unsigned ctl = tid >> 7, idx = tid & 127;
      const unsigned row = idx >> 3, cp = (idx & 7) << 1;
      const unsigned b = g*MB + row;
      float hn2[2];
      #pragma unroll
      for (int cc = 0; cc < 2; ++cc) {
        unsigned col = cp + cc;
        unsigned e = row*16 + col;
        float pr = 0.f, pz = 0.f, pnx = 0.f, pnh = 0.f;
        #pragma unroll
        for (int qq = 0; qq < 4; ++qq) {
          const float* pbase = P + (ctl*16 + qq)*256 + e;
          pr  += pbase[0];
          pz  += pbase[1024];
          pnx += pbase[2048];
          pnh += pbase[3072];
        }
        unsigned lc = ctl*16 + col;
        float r = 1.f/(1.f + __expf(-(pr + biasR[lc])));
        float z = 1.f/(1.f + __expf(-(pz + biasZ[lc])));
        float nin = pnx + biasNX[lc] + r*(pnh + biasNH[lc]);
        float e2 = __expf(2.f*nin);
        float n = 1.f - 2.f/(e2 + 1.f);             // tanh
        unsigned hcol = colbase + lc;
        float hold = bf2f(*(const unsigned short*)((char*)Ah + ah_addr(row, hcol)));
        hn2[cc] = (1.f - z)*n + z*hold;
      }
      unsigned hcol0 = colbase + ctl*16 + cp;
      *(float2*)(out + (size_t)b*SHq + (size_t)(t+1)*Hq + hcol0) = make_float2(hn2[0], hn2[1]);
      if (t == TSTEPS-1)
        *(float2*)(out + (size_t)Bq*SHq + (size_t)b*Hq + hcol0) = make_float2(hn2[0], hn2[1]);
      unsigned pv = (unsigned)f2bf(hn2[0]) | ((unsigned)f2bf(hn2[1]) << 16);
      __hip_atomic_store((unsigned*)(hd + (size_t)b*Hq + hcol0), pv,
                         __ATOMIC_RELAXED, __HIP_MEMORY_SCOPE_AGENT);
    }

    if (t < TSTEPS-1) group_barrier(bar, 32u*(unsigned)(t+2));
    cur ^= 1;
  }
}

extern "C" void kernel_launch(void* const* d_in, const int* in_sizes, int n_in,
                              void* d_out, int out_size, void* d_ws, size_t ws_size,
                              hipStream_t stream) {
  const float* x     = (const float*)d_in[0];
  const float* h0    = (const float*)d_in[1];
  const float* w_ir  = (const float*)d_in[2];
  const float* w_iz  = (const float*)d_in[3];
  const float* w_in_ = (const float*)d_in[4];
  const float* b_ir  = (const float*)d_in[5];
  const float* b_iz  = (const float*)d_in[6];
  const float* b_in_ = (const float*)d_in[7];
  const float* w_hr  = (const float*)d_in[8];
  const float* w_hz  = (const float*)d_in[9];
  const float* w_hn  = (const float*)d_in[10];
  const float* b_hr  = (const float*)d_in[11];
  const float* b_hz  = (const float*)d_in[12];
  const float* b_hn  = (const float*)d_in[13];
  float* out = (float*)d_out;

  // zero the 4 group-barrier counters (first 1 KB of ws)
  hipMemsetAsync(d_ws, 0, 1024, stream);

  void* args[] = { (void*)&x, (void*)&h0, (void*)&w_ir, (void*)&w_iz, (void*)&w_in_,
                   (void*)&b_ir, (void*)&b_iz, (void*)&b_in_, (void*)&w_hr, (void*)&w_hz,
                   (void*)&w_hn, (void*)&b_hr, (void*)&b_hz, (void*)&b_hn,
                   (void*)&out, (void*)&d_ws };
  hipLaunchCooperativeKernel((void*)gru_kernel, dim3(128), dim3(512), args, 0, stream);
}

// Round 2
// 3180.732 us; speedup vs baseline: 1.3130x; 1.3130x over previous
//
#include <hip/hip_runtime.h>
#include <hip/hip_bf16.h>

typedef __bf16 bf16x8 __attribute__((ext_vector_type(8)));
typedef float  f32x4  __attribute__((ext_vector_type(4)));

#define Bq 64
#define Sq 512
#define Iq 512
#define Hq 1024
#define TSTEPS 511
#define MB 16          // batches per group
#define NCOLS 32       // h-columns per block
#define SHq (Sq*Hq)

__device__ inline unsigned short f2bf(float f){ return __builtin_bit_cast(unsigned short, (__bf16)f); }
__device__ inline float bf2f(unsigned short u){ return (float)__builtin_bit_cast(__bf16, u); }

// swizzled LDS byte addresses (break the 2048B/1024B row-stride bank conflict)
__device__ inline unsigned ah_addr(unsigned row, unsigned k){ return ((row<<11) + (k<<1)) ^ ((row&7)<<4); }
__device__ inline unsigned ax_addr(unsigned row, unsigned k){ return ((row<<10) + (k<<1)) ^ ((row&7)<<4); }

__device__ inline bf16x8 load_wfrag(const float* p){
  float4 a = *(const float4*)p;
  float4 b = *(const float4*)(p+4);
  bf16x8 w;
  w[0]=(__bf16)a.x; w[1]=(__bf16)a.y; w[2]=(__bf16)a.z; w[3]=(__bf16)a.w;
  w[4]=(__bf16)b.x; w[5]=(__bf16)b.y; w[6]=(__bf16)b.z; w[7]=(__bf16)b.w;
  return w;
}

__global__ __launch_bounds__(512, 2) void gru_kernel(
    const float* __restrict__ x, const float* __restrict__ h0,
    const float* __restrict__ w_ir, const float* __restrict__ w_iz, const float* __restrict__ w_in_,
    const float* __restrict__ b_ir, const float* __restrict__ b_iz, const float* __restrict__ b_in_,
    const float* __restrict__ w_hr, const float* __restrict__ w_hz, const float* __restrict__ w_hn,
    const float* __restrict__ b_hr, const float* __restrict__ b_hz, const float* __restrict__ b_hn,
    float* __restrict__ out, void* ws)
{
  __shared__ unsigned short Ah[MB*Hq];   // 32 KB, swizzled
  __shared__ unsigned short Ax[MB*Iq];   // 16 KB, swizzled
  __shared__ float P[2*4*4*256];         // 32 KB partials [ct][gate][q][16x16]
  __shared__ float biasR[NCOLS], biasZ[NCOLS], biasNX[NCOLS], biasNH[NCOLS];

  const unsigned tid    = threadIdx.x;
  const unsigned bid    = blockIdx.x;
  const unsigned g      = bid & 3;        // batch group
  const unsigned colblk = bid >> 2;       // 0..31
  const unsigned colbase= colblk * NCOLS;
  const unsigned lane   = tid & 63;
  const unsigned wave   = tid >> 6;
  const unsigned ct     = wave >> 2;      // 16-col tile (0/1)
  const unsigned q      = wave & 3;       // K quarter
  const unsigned l15    = lane & 15;
  const unsigned l4     = lane >> 4;

  // ws layout: flags for group g at dwords [g*64 .. g*64+31]; h buffers after 1KB
  unsigned* flags = (unsigned*)ws + (size_t)g*64;
  unsigned short* hb0 = (unsigned short*)((char*)ws + 1024);
  unsigned short* hb1 = hb0 + Bq*Hq;

  if (tid < NCOLS) {
    unsigned c = colbase + tid;
    biasR[tid]  = b_ir[c] + b_hr[c];
    biasZ[tid]  = b_iz[c] + b_hz[c];
    biasNX[tid] = b_in_[c];
    biasNH[tid] = b_hn[c];
  }

  // ---- init: this block writes ITS OWN columns of h0 -> hb0 and out[:,0,:] ----
  if (tid < 256) {
    unsigned row = tid >> 4, cp = (tid & 15) << 1;
    unsigned b = g*MB + row;
    unsigned hcol = colbase + cp;
    float2 v = *(const float2*)(h0 + (size_t)b*Hq + hcol);
    *(float2*)(out + (size_t)b*SHq + hcol) = v;
    unsigned pv = (unsigned)f2bf(v.x) | ((unsigned)f2bf(v.y) << 16);
    __hip_atomic_store((unsigned*)(hb0 + (size_t)b*Hq + hcol), pv,
                       __ATOMIC_RELAXED, __HIP_MEMORY_SCOPE_AGENT);
  }
  __syncthreads();
  if (tid == 0)
    __hip_atomic_store(flags + colblk, 1u, __ATOMIC_RELEASE, __HIP_MEMORY_SCOPE_AGENT);

  // ---- stationary weight fragments in registers ----
  // B-frag (16x16x32): col = lane&15, k = (lane>>4)*8 + [0..7]
  const unsigned hcf = colbase + ct*16 + l15;
  bf16x8 wRX[4], wZX[4], wNX[4];   // x-parts, K=512 (4 ksteps/wave)
  bf16x8 wRH[8], wZH[8], wNH[8];   // h-parts, K=1024 (8 ksteps/wave)
  #pragma unroll
  for (int j = 0; j < 4; ++j) {
    unsigned ks = q*4 + j;
    wRX[j] = load_wfrag(w_ir  + (size_t)hcf*Iq + ks*32 + l4*8);
    wZX[j] = load_wfrag(w_iz  + (size_t)hcf*Iq + ks*32 + l4*8);
    wNX[j] = load_wfrag(w_in_ + (size_t)hcf*Iq + ks*32 + l4*8);
  }
  #pragma unroll
  for (int j = 0; j < 8; ++j) {
    unsigned ks = q*8 + j;
    wRH[j] = load_wfrag(w_hr + (size_t)hcf*Hq + ks*32 + l4*8);
    wZH[j] = load_wfrag(w_hz + (size_t)hcf*Hq + ks*32 + l4*8);
    wNH[j] = load_wfrag(w_hn + (size_t)hcf*Hq + ks*32 + l4*8);
  }

  const unsigned srow = tid >> 5, sli = tid & 31;   // staging role: 16 rows x 32 lanes

  unsigned cur = 0;
  for (int t = 0; t < TSTEPS; ++t) {
    const unsigned short* hs = cur ? hb1 : hb0;
    unsigned short*       hd = cur ? hb0 : hb1;

    // ---- stage x_t (h-independent): lane-interleaved, conflict-free LDS writes ----
    {
      const float* xs = x + ((size_t)(g*MB+srow)*Sq + (size_t)(t+1))*Iq;
      #pragma unroll
      for (int i = 0; i < 4; ++i) {
        unsigned e0 = (sli + 32*i) * 4;              // 4 f32 elems -> 8B bf16
        float4 v = *(const float4*)(xs + e0);
        unsigned long long pv = (unsigned long long)f2bf(v.x)
                              | ((unsigned long long)f2bf(v.y) << 16)
                              | ((unsigned long long)f2bf(v.z) << 32)
                              | ((unsigned long long)f2bf(v.w) << 48);
        *(unsigned long long*)((char*)Ax + ax_addr(srow, e0)) = pv;
      }
    }

    // ---- wait for h^(t): contention-free flag poll (one coalesced 128B load/iter) ----
    if (tid < 32) {
      unsigned tgt = (unsigned)t + 1;
      for (;;) {
        unsigned v = __hip_atomic_load(flags + tid, __ATOMIC_RELAXED, __HIP_MEMORY_SCOPE_AGENT);
        if (__all((int)(v >= tgt))) break;
      }
      __builtin_amdgcn_fence(__ATOMIC_ACQUIRE, "agent");
    }
    __syncthreads();   // S1: Ax staged + h visible

    // ---- issue h global loads (64B/thread), overlap with x-part MFMAs ----
    unsigned long long hv[8];
    {
      const unsigned long long* srcs = (const unsigned long long*)(hs + (size_t)(g*MB+srow)*Hq);
      #pragma unroll
      for (int i = 0; i < 8; ++i)
        hv[i] = __hip_atomic_load(srcs + sli + 32*i, __ATOMIC_RELAXED, __HIP_MEMORY_SCOPE_AGENT);
    }

    f32x4 accR={0.f,0.f,0.f,0.f}, accZ={0.f,0.f,0.f,0.f}, accNX={0.f,0.f,0.f,0.f}, accNH={0.f,0.f,0.f,0.f};
    #pragma unroll
    for (int j = 0; j < 4; ++j) {
      unsigned ks = q*4 + j;
      bf16x8 a = *(const bf16x8*)((char*)Ax + ax_addr(l15, ks*32 + l4*8));
      accR  = __builtin_amdgcn_mfma_f32_16x16x32_bf16(a, wRX[j], accR, 0, 0, 0);
      accZ  = __builtin_amdgcn_mfma_f32_16x16x32_bf16(a, wZX[j], accZ, 0, 0, 0);
      accNX = __builtin_amdgcn_mfma_f32_16x16x32_bf16(a, wNX[j], accNX, 0, 0, 0);
    }

    // ---- write h to LDS (lane-interleaved, conflict-free) ----
    #pragma unroll
    for (int i = 0; i < 8; ++i)
      *(unsigned long long*)((char*)Ah + ah_addr(srow, (sli + 32*i)*4)) = hv[i];
    __syncthreads();   // S2: Ah ready

    // ---- h-part MFMAs ----
    #pragma unroll
    for (int j = 0; j < 8; ++j) {
      unsigned ks = q*8 + j;
      bf16x8 a = *(const bf16x8*)((char*)Ah + ah_addr(l15, ks*32 + l4*8));
      accR  = __builtin_amdgcn_mfma_f32_16x16x32_bf16(a, wRH[j], accR, 0, 0, 0);
      accZ  = __builtin_amdgcn_mfma_f32_16x16x32_bf16(a, wZH[j], accZ, 0, 0, 0);
      accNH = __builtin_amdgcn_mfma_f32_16x16x32_bf16(a, wNH[j], accNH, 0, 0, 0);
    }

    // ---- partials to LDS (C layout: col=lane&15, row=(lane>>4)*4+i) ----
    {
      float* base = P + (ct*16 + q)*256;
      #pragma unroll
      for (int i = 0; i < 4; ++i) {
        unsigned e = (l4*4 + i)*16 + l15;
        base[0    + e] = accR[i];
        base[1024 + e] = accZ[i];
        base[2048 + e] = accNX[i];
        base[3072 + e] = accNH[i];
      }
    }
    __syncthreads();   // S3

    // ---- reduce + gates + stores ----
    if (tid < 256) {
      const unsigned ctl = tid >> 7, idx = tid & 127;
      const unsigned row = idx >> 3, cp = (idx & 7) << 1;
      const unsigned b = g*MB + row;
      float hn2[2];
      #pragma unroll
      for (int cc = 0; cc < 2; ++cc) {
        unsigned col = cp + cc;
        unsigned e = row*16 + col;
        float pr = 0.f, pz = 0.f, pnx = 0.f, pnh = 0.f;
        #pragma unroll
        for (int qq = 0; qq < 4; ++qq) {
          const float* pbase = P + (ctl*16 + qq)*256 + e;
          pr  += pbase[0];
          pz  += pbase[1024];
          pnx += pbase[2048];
          pnh += pbase[3072];
        }
        unsigned lc = ctl*16 + col;
        float r = 1.f/(1.f + __expf(-(pr + biasR[lc])));
        float z = 1.f/(1.f + __expf(-(pz + biasZ[lc])));
        float nin = pnx + biasNX[lc] + r*(pnh + biasNH[lc]);
        float e2 = __expf(2.f*nin);
        float n = 1.f - 2.f/(e2 + 1.f);             // tanh
        unsigned hcol = colbase + lc;
        float hold = bf2f(*(const unsigned short*)((char*)Ah + ah_addr(row, hcol)));
        hn2[cc] = (1.f - z)*n + z*hold;
      }
      unsigned hcol0 = colbase + ctl*16 + cp;
      *(float2*)(out + (size_t)b*SHq + (size_t)(t+1)*Hq + hcol0) = make_float2(hn2[0], hn2[1]);
      if (t == TSTEPS-1)
        *(float2*)(out + (size_t)Bq*SHq + (size_t)b*Hq + hcol0) = make_float2(hn2[0], hn2[1]);
      unsigned pv = (unsigned)f2bf(hn2[0]) | ((unsigned)f2bf(hn2[1]) << 16);
      __hip_atomic_store((unsigned*)(hd + (size_t)b*Hq + hcol0), pv,
                         __ATOMIC_RELAXED, __HIP_MEMORY_SCOPE_AGENT);
    }
    __syncthreads();   // S4: all h stores drained (vmcnt(0) before s_barrier)
    if (tid == 0 && t < TSTEPS-1)
      __hip_atomic_store(flags + colblk, (unsigned)t + 2, __ATOMIC_RELEASE, __HIP_MEMORY_SCOPE_AGENT);

    cur ^= 1;
  }
}

extern "C" void kernel_launch(void* const* d_in, const int* in_sizes, int n_in,
                              void* d_out, int out_size, void* d_ws, size_t ws_size,
                              hipStream_t stream) {
  const float* x     = (const float*)d_in[0];
  const float* h0    = (const float*)d_in[1];
  const float* w_ir  = (const float*)d_in[2];
  const float* w_iz  = (const float*)d_in[3];
  const float* w_in_ = (const float*)d_in[4];
  const float* b_ir  = (const float*)d_in[5];
  const float* b_iz  = (const float*)d_in[6];
  const float* b_in_ = (const float*)d_in[7];
  const float* w_hr  = (const float*)d_in[8];
  const float* w_hz  = (const float*)d_in[9];
  const float* w_hn  = (const float*)d_in[10];
  const float* b_hr  = (const float*)d_in[11];
  const float* b_hz  = (const float*)d_in[12];
  const float* b_hn  = (const float*)d_in[13];
  float* out = (float*)d_out;

  // zero the flag arrays (first 1 KB of ws)
  hipMemsetAsync(d_ws, 0, 1024, stream);

  void* args[] = { (void*)&x, (void*)&h0, (void*)&w_ir, (void*)&w_iz, (void*)&w_in_,
                   (void*)&b_ir, (void*)&b_iz, (void*)&b_in_, (void*)&w_hr, (void*)&w_hz,
                   (void*)&w_hn, (void*)&b_hr, (void*)&b_hz, (void*)&b_hn,
                   (void*)&out, (void*)&d_ws };
  hipLaunchCooperativeKernel((void*)gru_kernel, dim3(128), dim3(512), args, 0, stream);
}

// Round 3
// 1497.049 us; speedup vs baseline: 2.7897x; 2.1247x over previous
//
#include <hip/hip_runtime.h>
#include <hip/hip_bf16.h>

typedef __bf16 bf16x8 __attribute__((ext_vector_type(8)));
typedef float  f32x4  __attribute__((ext_vector_type(4)));

#define Bq 64
#define Sq 512
#define Iq 512
#define Hq 1024
#define TSTEPS 511
#define MB 16          // batches per group
#define NCOLS 32       // h-columns per block
#define SHq (Sq*Hq)

__device__ inline unsigned short f2bf(float f){ return __builtin_bit_cast(unsigned short, (__bf16)f); }
__device__ inline float bf2f(unsigned short u){ return (float)__builtin_bit_cast(__bf16, u); }

// swizzled LDS byte addresses (break the 2048B/1024B row-stride bank conflict)
__device__ inline unsigned ah_addr(unsigned row, unsigned k){ return ((row<<11) + (k<<1)) ^ ((row&7)<<4); }
__device__ inline unsigned ax_addr(unsigned row, unsigned k){ return ((row<<10) + (k<<1)) ^ ((row&7)<<4); }

__device__ inline bf16x8 load_wfrag(const float* p){
  float4 a = *(const float4*)p;
  float4 b = *(const float4*)(p+4);
  bf16x8 w;
  w[0]=(__bf16)a.x; w[1]=(__bf16)a.y; w[2]=(__bf16)a.z; w[3]=(__bf16)a.w;
  w[4]=(__bf16)b.x; w[5]=(__bf16)b.y; w[6]=(__bf16)b.z; w[7]=(__bf16)b.w;
  return w;
}

__global__ __launch_bounds__(512, 2) void gru_kernel(
    const float* __restrict__ x, const float* __restrict__ h0,
    const float* __restrict__ w_ir, const float* __restrict__ w_iz, const float* __restrict__ w_in_,
    const float* __restrict__ b_ir, const float* __restrict__ b_iz, const float* __restrict__ b_in_,
    const float* __restrict__ w_hr, const float* __restrict__ w_hz, const float* __restrict__ w_hn,
    const float* __restrict__ b_hr, const float* __restrict__ b_hz, const float* __restrict__ b_hn,
    float* __restrict__ out, void* ws)
{
  __shared__ unsigned short Ah[MB*Hq];   // 32 KB, swizzled
  __shared__ unsigned short Ax[MB*Iq];   // 16 KB, swizzled
  __shared__ float P[2*4*4*256];         // 32 KB partials [ct][gate][q][16x16]
  __shared__ float biasR[NCOLS], biasZ[NCOLS], biasNX[NCOLS], biasNH[NCOLS];

  const unsigned tid    = threadIdx.x;
  const unsigned bid    = blockIdx.x;
  const unsigned g      = bid & 3;        // batch group (blocks interleaved -> 2 XCDs/group)
  const unsigned colblk = bid >> 2;       // 0..31
  const unsigned colbase= colblk * NCOLS;
  const unsigned lane   = tid & 63;
  const unsigned wave   = tid >> 6;
  const unsigned ct     = wave >> 2;      // 16-col tile (0/1)
  const unsigned q      = wave & 3;       // K quarter
  const unsigned l15    = lane & 15;
  const unsigned l4     = lane >> 4;

  // ws layout: flags for group g at dwords [g*64 .. g*64+31]; h buffers after 1KB
  unsigned* flags = (unsigned*)ws + (size_t)g*64;
  unsigned short* hb0 = (unsigned short*)((char*)ws + 1024);
  unsigned short* hb1 = hb0 + Bq*Hq;

  if (tid < NCOLS) {
    unsigned c = colbase + tid;
    biasR[tid]  = b_ir[c] + b_hr[c];
    biasZ[tid]  = b_iz[c] + b_hz[c];
    biasNX[tid] = b_in_[c];
    biasNH[tid] = b_hn[c];
  }

  // ---- init: this block writes ITS OWN columns of h0 -> hb0 and out[:,0,:] ----
  // All cross-block data (h, flags) moves ONLY through agent-scope relaxed
  // atomics (sc1 -> coherence point). No fences: release ordering comes from
  // the vmcnt(0) drain implied by __syncthreads before the flag store;
  // acquire ordering from the control dependency poll->barrier->loads.
  if (tid < 256) {
    unsigned row = tid >> 4, cp = (tid & 15) << 1;
    unsigned b = g*MB + row;
    unsigned hcol = colbase + cp;
    float2 v = *(const float2*)(h0 + (size_t)b*Hq + hcol);
    *(float2*)(out + (size_t)b*SHq + hcol) = v;
    unsigned pv = (unsigned)f2bf(v.x) | ((unsigned)f2bf(v.y) << 16);
    __hip_atomic_store((unsigned*)(hb0 + (size_t)b*Hq + hcol), pv,
                       __ATOMIC_RELAXED, __HIP_MEMORY_SCOPE_AGENT);
  }
  __syncthreads();
  if (tid == 0)
    __hip_atomic_store(flags + colblk, 1u, __ATOMIC_RELAXED, __HIP_MEMORY_SCOPE_AGENT);

  // ---- stationary weight fragments in registers ----
  // B-frag (16x16x32): col = lane&15, k = (lane>>4)*8 + [0..7]
  const unsigned hcf = colbase + ct*16 + l15;
  bf16x8 wRX[4], wZX[4], wNX[4];   // x-parts, K=512 (4 ksteps/wave)
  bf16x8 wRH[8], wZH[8], wNH[8];   // h-parts, K=1024 (8 ksteps/wave)
  #pragma unroll
  for (int j = 0; j < 4; ++j) {
    unsigned ks = q*4 + j;
    wRX[j] = load_wfrag(w_ir  + (size_t)hcf*Iq + ks*32 + l4*8);
    wZX[j] = load_wfrag(w_iz  + (size_t)hcf*Iq + ks*32 + l4*8);
    wNX[j] = load_wfrag(w_in_ + (size_t)hcf*Iq + ks*32 + l4*8);
  }
  #pragma unroll
  for (int j = 0; j < 8; ++j) {
    unsigned ks = q*8 + j;
    wRH[j] = load_wfrag(w_hr + (size_t)hcf*Hq + ks*32 + l4*8);
    wZH[j] = load_wfrag(w_hz + (size_t)hcf*Hq + ks*32 + l4*8);
    wNH[j] = load_wfrag(w_hn + (size_t)hcf*Hq + ks*32 + l4*8);
  }

  const unsigned srow = tid >> 5, sli = tid & 31;   // staging role: 16 rows x 32 lanes

  unsigned cur = 0;
  for (int t = 0; t < TSTEPS; ++t) {
    const unsigned short* hs = cur ? hb1 : hb0;
    unsigned short*       hd = cur ? hb0 : hb1;

    // ---- stage x_t (h-independent): lane-interleaved, conflict-free LDS writes ----
    {
      const float* xs = x + ((size_t)(g*MB+srow)*Sq + (size_t)(t+1))*Iq;
      #pragma unroll
      for (int i = 0; i < 4; ++i) {
        unsigned e0 = (sli + 32*i) * 4;              // 4 f32 elems -> 8B bf16
        float4 v = *(const float4*)(xs + e0);
        unsigned long long pv = (unsigned long long)f2bf(v.x)
                              | ((unsigned long long)f2bf(v.y) << 16)
                              | ((unsigned long long)f2bf(v.z) << 32)
                              | ((unsigned long long)f2bf(v.w) << 48);
        *(unsigned long long*)((char*)Ax + ax_addr(srow, e0)) = pv;
      }
    }

    // ---- wait for h^(t): contention-free relaxed flag poll, no fence ----
    if (tid < 32) {
      unsigned tgt = (unsigned)t + 1;
      for (;;) {
        unsigned v = __hip_atomic_load(flags + tid, __ATOMIC_RELAXED, __HIP_MEMORY_SCOPE_AGENT);
        if (__all((int)(v >= tgt))) break;
      }
    }
    __syncthreads();   // S1: Ax staged + h flags observed

    // ---- issue h global loads (64B/thread), overlap with x-part MFMAs ----
    unsigned long long hv[8];
    {
      const unsigned long long* srcs = (const unsigned long long*)(hs + (size_t)(g*MB+srow)*Hq);
      #pragma unroll
      for (int i = 0; i < 8; ++i)
        hv[i] = __hip_atomic_load(srcs + sli + 32*i, __ATOMIC_RELAXED, __HIP_MEMORY_SCOPE_AGENT);
    }

    f32x4 accR={0.f,0.f,0.f,0.f}, accZ={0.f,0.f,0.f,0.f}, accNX={0.f,0.f,0.f,0.f}, accNH={0.f,0.f,0.f,0.f};
    #pragma unroll
    for (int j = 0; j < 4; ++j) {
      unsigned ks = q*4 + j;
      bf16x8 a = *(const bf16x8*)((char*)Ax + ax_addr(l15, ks*32 + l4*8));
      accR  = __builtin_amdgcn_mfma_f32_16x16x32_bf16(a, wRX[j], accR, 0, 0, 0);
      accZ  = __builtin_amdgcn_mfma_f32_16x16x32_bf16(a, wZX[j], accZ, 0, 0, 0);
      accNX = __builtin_amdgcn_mfma_f32_16x16x32_bf16(a, wNX[j], accNX, 0, 0, 0);
    }

    // ---- write h to LDS (lane-interleaved, conflict-free) ----
    #pragma unroll
    for (int i = 0; i < 8; ++i)
      *(unsigned long long*)((char*)Ah + ah_addr(srow, (sli + 32*i)*4)) = hv[i];
    __syncthreads();   // S2: Ah ready

    // ---- h-part MFMAs ----
    #pragma unroll
    for (int j = 0; j < 8; ++j) {
      unsigned ks = q*8 + j;
      bf16x8 a = *(const bf16x8*)((char*)Ah + ah_addr(l15, ks*32 + l4*8));
      accR  = __builtin_amdgcn_mfma_f32_16x16x32_bf16(a, wRH[j], accR, 0, 0, 0);
      accZ  = __builtin_amdgcn_mfma_f32_16x16x32_bf16(a, wZH[j], accZ, 0, 0, 0);
      accNH = __builtin_amdgcn_mfma_f32_16x16x32_bf16(a, wNH[j], accNH, 0, 0, 0);
    }

    // ---- partials to LDS (C layout: col=lane&15, row=(lane>>4)*4+i) ----
    {
      float* base = P + (ct*16 + q)*256;
      #pragma unroll
      for (int i = 0; i < 4; ++i) {
        unsigned e = (l4*4 + i)*16 + l15;
        base[0    + e] = accR[i];
        base[1024 + e] = accZ[i];
        base[2048 + e] = accNX[i];
        base[3072 + e] = accNH[i];
      }
    }
    __syncthreads();   // S3

    // ---- reduce + gates + stores ----
    if (tid < 256) {
      const unsigned ctl = tid >> 7, idx = tid & 127;
      const unsigned row = idx >> 3, cp = (idx & 7) << 1;
      const unsigned b = g*MB + row;
      float hn2[2];
      #pragma unroll
      for (int cc = 0; cc < 2; ++cc) {
        unsigned col = cp + cc;
        unsigned e = row*16 + col;
        float pr = 0.f, pz = 0.f, pnx = 0.f, pnh = 0.f;
        #pragma unroll
        for (int qq = 0; qq < 4; ++qq) {
          const float* pbase = P + (ctl*16 + qq)*256 + e;
          pr  += pbase[0];
          pz  += pbase[1024];
          pnx += pbase[2048];
          pnh += pbase[3072];
        }
        unsigned lc = ctl*16 + col;
        float r = 1.f/(1.f + __expf(-(pr + biasR[lc])));
        float z = 1.f/(1.f + __expf(-(pz + biasZ[lc])));
        float nin = pnx + biasNX[lc] + r*(pnh + biasNH[lc]);
        float e2 = __expf(2.f*nin);
        float n = 1.f - 2.f/(e2 + 1.f);             // tanh
        unsigned hcol = colbase + lc;
        float hold = bf2f(*(const unsigned short*)((char*)Ah + ah_addr(row, hcol)));
        hn2[cc] = (1.f - z)*n + z*hold;
      }
      unsigned hcol0 = colbase + ctl*16 + cp;
      *(float2*)(out + (size_t)b*SHq + (size_t)(t+1)*Hq + hcol0) = make_float2(hn2[0], hn2[1]);
      if (t == TSTEPS-1)
        *(float2*)(out + (size_t)Bq*SHq + (size_t)b*Hq + hcol0) = make_float2(hn2[0], hn2[1]);
      unsigned pv = (unsigned)f2bf(hn2[0]) | ((unsigned)f2bf(hn2[1]) << 16);
      __hip_atomic_store((unsigned*)(hd + (size_t)b*Hq + hcol0), pv,
                         __ATOMIC_RELAXED, __HIP_MEMORY_SCOPE_AGENT);
    }
    __syncthreads();   // S4: every wave drains vmcnt(0) at this barrier -> h at L3
    if (tid == 0 && t < TSTEPS-1)
      __hip_atomic_store(flags + colblk, (unsigned)t + 2, __ATOMIC_RELAXED, __HIP_MEMORY_SCOPE_AGENT);

    cur ^= 1;
  }
}

extern "C" void kernel_launch(void* const* d_in, const int* in_sizes, int n_in,
                              void* d_out, int out_size, void* d_ws, size_t ws_size,
                              hipStream_t stream) {
  const float* x     = (const float*)d_in[0];
  const float* h0    = (const float*)d_in[1];
  const float* w_ir  = (const float*)d_in[2];
  const float* w_iz  = (const float*)d_in[3];
  const float* w_in_ = (const float*)d_in[4];
  const float* b_ir  = (const float*)d_in[5];
  const float* b_iz  = (const float*)d_in[6];
  const float* b_in_ = (const float*)d_in[7];
  const float* w_hr  = (const float*)d_in[8];
  const float* w_hz  = (const float*)d_in[9];
  const float* w_hn  = (const float*)d_in[10];
  const float* b_hr  = (const float*)d_in[11];
  const float* b_hz  = (const float*)d_in[12];
  const float* b_hn  = (const float*)d_in[13];
  float* out = (float*)d_out;

  // zero the flag arrays (first 1 KB of ws)
  hipMemsetAsync(d_ws, 0, 1024, stream);

  void* args[] = { (void*)&x, (void*)&h0, (void*)&w_ir, (void*)&w_iz, (void*)&w_in_,
                   (void*)&b_ir, (void*)&b_iz, (void*)&b_in_, (void*)&w_hr, (void*)&w_hz,
                   (void*)&w_hn, (void*)&b_hr, (void*)&b_hz, (void*)&b_hn,
                   (void*)&out, (void*)&d_ws };
  hipLaunchCooperativeKernel((void*)gru_kernel, dim3(128), dim3(512), args, 0, stream);
}

// Round 5
// 1325.341 us; speedup vs baseline: 3.1512x; 1.1296x over previous
//
#include <hip/hip_runtime.h>
#include <hip/hip_bf16.h>

typedef __bf16 bf16x8 __attribute__((ext_vector_type(8)));
typedef float  f32x4  __attribute__((ext_vector_type(4)));

#define Bq 64
#define Sq 512
#define Iq 512
#define Hq 1024
#define TSTEPS 511
#define MB 16          // batches per group
#define NCOLS 32       // h-columns per block
#define SHq (Sq*Hq)
#define TAGM 0x0001000100010001ull

__device__ inline unsigned short f2bf(float f){ return __builtin_bit_cast(unsigned short, (__bf16)f); }
__device__ inline float bf2f(unsigned short u){ return (float)__builtin_bit_cast(__bf16, u); }

// swizzled LDS byte addresses (break the 2048B/1024B row-stride bank conflict)
__device__ inline unsigned ah_addr(unsigned row, unsigned k){ return ((row<<11) + (k<<1)) ^ ((row&7)<<4); }
__device__ inline unsigned ax_addr(unsigned row, unsigned k){ return ((row<<10) + (k<<1)) ^ ((row&7)<<4); }

__device__ inline bf16x8 load_wfrag(const float* p){
  float4 a = *(const float4*)p;
  float4 b = *(const float4*)(p+4);
  bf16x8 w;
  w[0]=(__bf16)a.x; w[1]=(__bf16)a.y; w[2]=(__bf16)a.z; w[3]=(__bf16)a.w;
  w[4]=(__bf16)b.x; w[5]=(__bf16)b.y; w[6]=(__bf16)b.z; w[7]=(__bf16)b.w;
  return w;
}

// Tag protocol: h^s lives in buffer s&1; every stored bf16's LSB = (s>>1)&1.
// kernel_launch memsets both buffers to 0xFF (tag 1 = stale for t=0/1, and a
// bf16 NaN never interpretable as fresh data) BEFORE each run, so replays and
// the 0xAA ws-poison cannot alias a fresh tag. Induction on per-location
// coherence: at step t a consumer has previously observed the step t-2 value
// (or h0-publish / memset) at each address, whose tag != want; the only
// want-tagged value ordered after it is the genuine h^t store.
__global__ __launch_bounds__(512, 1) void gru_kernel(
    const float* __restrict__ x, const float* __restrict__ h0,
    const float* __restrict__ w_ir, const float* __restrict__ w_iz, const float* __restrict__ w_in_,
    const float* __restrict__ b_ir, const float* __restrict__ b_iz, const float* __restrict__ b_in_,
    const float* __restrict__ w_hr, const float* __restrict__ w_hz, const float* __restrict__ w_hn,
    const float* __restrict__ b_hr, const float* __restrict__ b_hz, const float* __restrict__ b_hn,
    float* __restrict__ out, void* ws)
{
  __shared__ unsigned short Ah[MB*Hq];   // 32 KB, swizzled
  __shared__ unsigned short Ax[MB*Iq];   // 16 KB, swizzled
  __shared__ float P[2*4*4*256];         // 32 KB partials [ct][gate][q][16x16]
  __shared__ float biasR[NCOLS], biasZ[NCOLS], biasNX[NCOLS], biasNH[NCOLS];

  const unsigned tid    = threadIdx.x;
  const unsigned bid    = blockIdx.x;
  const unsigned g      = bid & 3;        // batch group
  const unsigned colblk = bid >> 2;       // 0..31
  const unsigned colbase= colblk * NCOLS;
  const unsigned lane   = tid & 63;
  const unsigned wave   = tid >> 6;
  const unsigned ct     = wave >> 2;      // 16-col tile (0/1)
  const unsigned q      = wave & 3;       // K quarter
  const unsigned l15    = lane & 15;
  const unsigned l4     = lane >> 4;
  const unsigned srow   = tid >> 5, sli = tid & 31;   // 16 rows x 32 lanes roles

  unsigned short* hb0 = (unsigned short*)ws;          // ping-pong tagged h buffers
  unsigned short* hb1 = hb0 + Bq*Hq;

  if (tid < NCOLS) {
    unsigned c = colbase + tid;
    biasR[tid]  = b_ir[c] + b_hr[c];
    biasZ[tid]  = b_iz[c] + b_hz[c];
    biasNX[tid] = b_in_[c];
    biasNH[tid] = b_hn[c];
  }

  // ---- init: publish own h0 columns (tag 0) + out[:,0,:] ----
  {
    unsigned b = g*MB + srow, hcol = colbase + sli;
    float v = h0[(size_t)b*Hq + hcol];
    out[(size_t)b*SHq + hcol] = v;
    unsigned short u = (unsigned short)(f2bf(v) & ~1u);   // tag 0
    __hip_atomic_store(hb0 + (size_t)b*Hq + hcol, u,
                       __ATOMIC_RELAXED, __HIP_MEMORY_SCOPE_AGENT);
  }

  // ---- stationary weight fragments in registers ----
  // B-frag (16x16x32): col = lane&15, k = (lane>>4)*8 + [0..7]
  const unsigned hcf = colbase + ct*16 + l15;
  bf16x8 wRX[4], wZX[4], wNX[4];   // x-parts, K=512 (4 ksteps/wave)
  bf16x8 wRH[8], wZH[8], wNH[8];   // h-parts, K=1024 (8 ksteps/wave)
  #pragma unroll
  for (int j = 0; j < 4; ++j) {
    unsigned ks = q*4 + j;
    wRX[j] = load_wfrag(w_ir  + (size_t)hcf*Iq + ks*32 + l4*8);
    wZX[j] = load_wfrag(w_iz  + (size_t)hcf*Iq + ks*32 + l4*8);
    wNX[j] = load_wfrag(w_in_ + (size_t)hcf*Iq + ks*32 + l4*8);
  }
  #pragma unroll
  for (int j = 0; j < 8; ++j) {
    unsigned ks = q*8 + j;
    wRH[j] = load_wfrag(w_hr + (size_t)hcf*Hq + ks*32 + l4*8);
    wZH[j] = load_wfrag(w_hz + (size_t)hcf*Hq + ks*32 + l4*8);
    wNH[j] = load_wfrag(w_hn + (size_t)hcf*Hq + ks*32 + l4*8);
  }

  // ---- x prefetch for t=0 (x[:,1]) ----
  float4 xpf[4];
  {
    const float* xs = x + ((size_t)(g*MB+srow)*Sq + 1)*Iq;
    #pragma unroll
    for (int i = 0; i < 4; ++i) xpf[i] = *(const float4*)(xs + (sli + 32*i)*4);
  }

  for (int t = 0; t < TSTEPS; ++t) {
    const unsigned short* hs = (t & 1) ? hb1 : hb0;
    unsigned short*       hd = (t & 1) ? hb0 : hb1;
    const unsigned long long want = ((t >> 1) & 1) ? TAGM : 0ull;
    const unsigned tagd = ((t + 1) >> 1) & 1;

    // ---- write Ax from prefetched regs (prev iter's loads; S3(t-1) protects readers) ----
    #pragma unroll
    for (int i = 0; i < 4; ++i) {
      float4 v = xpf[i];
      unsigned long long pv = (unsigned long long)f2bf(v.x)
                            | ((unsigned long long)f2bf(v.y) << 16)
                            | ((unsigned long long)f2bf(v.z) << 32)
                            | ((unsigned long long)f2bf(v.w) << 48);
      *(unsigned long long*)((char*)Ax + ax_addr(srow, (sli + 32*i)*4)) = pv;
    }

    // ---- poll h^t directly: batched 8x8B loads; retry stale ones with backoff ----
    unsigned long long hv[8];
    const unsigned long long* srcs = (const unsigned long long*)(hs + (size_t)(g*MB+srow)*Hq);
    #pragma unroll
    for (int i = 0; i < 8; ++i)
      hv[i] = __hip_atomic_load(srcs + sli + 32*i, __ATOMIC_RELAXED, __HIP_MEMORY_SCOPE_AGENT);
    for (;;) {
      unsigned stale = 0;
      #pragma unroll
      for (int i = 0; i < 8; ++i)
        if ((hv[i] & TAGM) != want) stale |= 1u << i;
      if (!stale) break;
      __builtin_amdgcn_s_sleep(1);   // throttle the poll storm
      #pragma unroll
      for (int i = 0; i < 8; ++i)
        if (stale & (1u << i))
          hv[i] = __hip_atomic_load(srcs + sli + 32*i, __ATOMIC_RELAXED, __HIP_MEMORY_SCOPE_AGENT);
    }

    // ---- issue x prefetch for next iter (hidden under MFMA+reduce) ----
    {
      int tt = (t + 2 <= 511) ? (t + 2) : 511;
      const float* xs = x + ((size_t)(g*MB+srow)*Sq + (size_t)tt)*Iq;
      #pragma unroll
      for (int i = 0; i < 4; ++i) xpf[i] = *(const float4*)(xs + (sli + 32*i)*4);
    }

    // ---- h -> LDS (tagged bf16 used as-is; tag = 1 ulp) ----
    #pragma unroll
    for (int i = 0; i < 8; ++i)
      *(unsigned long long*)((char*)Ah + ah_addr(srow, (sli + 32*i)*4)) = hv[i];
    __syncthreads();   // S1: Ax + Ah ready

    // ---- MFMAs: 36/wave ----
    f32x4 accR={0.f,0.f,0.f,0.f}, accZ={0.f,0.f,0.f,0.f}, accNX={0.f,0.f,0.f,0.f}, accNH={0.f,0.f,0.f,0.f};
    #pragma unroll
    for (int j = 0; j < 4; ++j) {
      unsigned ks = q*4 + j;
      bf16x8 a = *(const bf16x8*)((char*)Ax + ax_addr(l15, ks*32 + l4*8));
      accR  = __builtin_amdgcn_mfma_f32_16x16x32_bf16(a, wRX[j], accR, 0, 0, 0);
      accZ  = __builtin_amdgcn_mfma_f32_16x16x32_bf16(a, wZX[j], accZ, 0, 0, 0);
      accNX = __builtin_amdgcn_mfma_f32_16x16x32_bf16(a, wNX[j], accNX, 0, 0, 0);
    }
    #pragma unroll
    for (int j = 0; j < 8; ++j) {
      unsigned ks = q*8 + j;
      bf16x8 a = *(const bf16x8*)((char*)Ah + ah_addr(l15, ks*32 + l4*8));
      accR  = __builtin_amdgcn_mfma_f32_16x16x32_bf16(a, wRH[j], accR, 0, 0, 0);
      accZ  = __builtin_amdgcn_mfma_f32_16x16x32_bf16(a, wZH[j], accZ, 0, 0, 0);
      accNH = __builtin_amdgcn_mfma_f32_16x16x32_bf16(a, wNH[j], accNH, 0, 0, 0);
    }

    // ---- pre-read hold (before S3 so no post-reduce barrier is needed) ----
    const unsigned rrow = srow, lc = sli;            // reduce role: 1 col/thread
    const unsigned hcol = colbase + lc;
    float hold = bf2f(*(const unsigned short*)((char*)Ah + ah_addr(rrow, hcol)));

    // ---- partials to LDS (C layout: col=lane&15, row=(lane>>4)*4+i) ----
    {
      float* base = P + (ct*16 + q)*256;
      #pragma unroll
      for (int i = 0; i < 4; ++i) {
        unsigned e = (l4*4 + i)*16 + l15;
        base[0    + e] = accR[i];
        base[1024 + e] = accZ[i];
        base[2048 + e] = accNX[i];
        base[3072 + e] = accNH[i];
      }
    }
    __syncthreads();   // S3

    // ---- reduce + gates + stores: 512 threads, 1 col each ----
    {
      const unsigned ctl = lc >> 4, col = lc & 15;
      const unsigned b = g*MB + rrow;
      const unsigned e = rrow*16 + col;
      float pr = 0.f, pz = 0.f, pnx = 0.f, pnh = 0.f;
      #pragma unroll
      for (int qq = 0; qq < 4; ++qq) {
        const float* pbase = P + (ctl*16 + qq)*256 + e;
        pr  += pbase[0];
        pz  += pbase[1024];
        pnx += pbase[2048];
        pnh += pbase[3072];
      }
      float r = 1.f/(1.f + __expf(-(pr + biasR[lc])));
      float z = 1.f/(1.f + __expf(-(pz + biasZ[lc])));
      float nin = pnx + biasNX[lc] + r*(pnh + biasNH[lc]);
      float e2 = __expf(2.f*nin);
      float n = 1.f - 2.f/(e2 + 1.f);             // tanh
      float hn = (1.f - z)*n + z*hold;

      // h store first (gates the group), tagged bf16
      unsigned short u = (unsigned short)((f2bf(hn) & ~1u) | tagd);
      __hip_atomic_store(hd + (size_t)b*Hq + hcol, u,
                         __ATOMIC_RELAXED, __HIP_MEMORY_SCOPE_AGENT);
      // out stores never drained on the chain
      out[(size_t)b*SHq + (size_t)(t+1)*Hq + hcol] = hn;
      if (t == TSTEPS-1)
        out[(size_t)Bq*SHq + (size_t)b*Hq + hcol] = hn;
    }
    // no S4: next iter's LDS writes are fenced by S3 (all MFMA/hold reads done),
    // and h-store visibility is absorbed by the consumers' data poll.
  }
}

extern "C" void kernel_launch(void* const* d_in, const int* in_sizes, int n_in,
                              void* d_out, int out_size, void* d_ws, size_t ws_size,
                              hipStream_t stream) {
  const float* x     = (const float*)d_in[0];
  const float* h0    = (const float*)d_in[1];
  const float* w_ir  = (const float*)d_in[2];
  const float* w_iz  = (const float*)d_in[3];
  const float* w_in_ = (const float*)d_in[4];
  const float* b_ir  = (const float*)d_in[5];
  const float* b_iz  = (const float*)d_in[6];
  const float* b_in_ = (const float*)d_in[7];
  const float* w_hr  = (const float*)d_in[8];
  const float* w_hz  = (const float*)d_in[9];
  const float* w_hn  = (const float*)d_in[10];
  const float* b_hr  = (const float*)d_in[11];
  const float* b_hz  = (const float*)d_in[12];
  const float* b_hn  = (const float*)d_in[13];
  float* out = (float*)d_out;

  // Precondition the tagged h ping-pong buffers to ALL-STALE (0xFFFF: tag 1,
  // bf16 NaN). Erases inter-replay leftovers and the harness's 0xAA poison
  // (0xAAAA would alias tag 0 = fresh for t=0/1).
  hipMemsetAsync(d_ws, 0xFF, (size_t)2 * Bq * Hq * sizeof(unsigned short), stream);

  void* args[] = { (void*)&x, (void*)&h0, (void*)&w_ir, (void*)&w_iz, (void*)&w_in_,
                   (void*)&b_ir, (void*)&b_iz, (void*)&b_in_, (void*)&w_hr, (void*)&w_hz,
                   (void*)&w_hn, (void*)&b_hr, (void*)&b_hz, (void*)&b_hn,
                   (void*)&out, (void*)&d_ws };
  hipLaunchCooperativeKernel((void*)gru_kernel, dim3(128), dim3(512), args, 0, stream);
}